// Round 5
// baseline (17761.772 us; speedup 1.0000x reference)
//
#include <hip/hip_runtime.h>
#include <cstdint>

#define N_TOT 30000
#define E_TOT 120000
#define G_TOT 1000

typedef unsigned short u16;
typedef unsigned int u32;
typedef __attribute__((ext_vector_type(8))) short short8;
typedef __attribute__((ext_vector_type(4))) float f32x4;

#define AS1 __attribute__((address_space(1)))
#define AS3 __attribute__((address_space(3)))

// async global->LDS, 16B per lane. LDS dest must be wave-uniform base + lane*16.
static __device__ __forceinline__ void gload_lds16(const void* g, void* l) {
  __builtin_amdgcn_global_load_lds((AS1 void*)(uintptr_t)g,
                                   (AS3 void*)(uint32_t)(uintptr_t)l, 16, 0, 0);
}

static __device__ __forceinline__ u16 f2bf(float f) {
  uint32_t u = __float_as_uint(f);
  uint32_t r = (u + 0x7fffu + ((u >> 16) & 1u)) >> 16;  // RTNE
  return (u16)r;
}
static __device__ __forceinline__ float bf2f(u16 v) {
  return __uint_as_float((uint32_t)v << 16);
}

// ---------------- deg (in-edges per dst), graph counts, src out-degree ------
__global__ void prep_kernel(const int* __restrict__ ei, const int* __restrict__ batch,
                            float* __restrict__ deg, float* __restrict__ gcnt,
                            int* __restrict__ sd) {
  int t = blockIdx.x * 256 + threadIdx.x;
  if (t < E_TOT) {
    atomicAdd(&deg[ei[E_TOT + t]], 1.0f);
    atomicAdd(&sd[ei[t]], 1);
  }
  if (t < N_TOT) atomicAdd(&gcnt[batch[t]], 1.0f);
}

// ---------------- exclusive scan of src out-degree (single block) ----------
__global__ void scan_kernel(const int* __restrict__ sd, int* __restrict__ off) {
  __shared__ int buf[1024];
  __shared__ int carry;
  const int t = threadIdx.x;
  if (t == 0) carry = 0;
  __syncthreads();
  for (int base = 0; base < N_TOT; base += 1024) {
    int v = base + t;
    int x = (v < N_TOT) ? sd[v] : 0;
    buf[t] = x;
    __syncthreads();
    for (int o = 1; o < 1024; o <<= 1) {
      int y = (t >= o) ? buf[t - o] : 0;
      __syncthreads();
      buf[t] += y;
      __syncthreads();
    }
    if (v < N_TOT) off[v] = carry + buf[t] - x;
    __syncthreads();
    if (t == 0) carry += buf[1023];
    __syncthreads();
  }
  if (t == 0) off[N_TOT] = carry;
}

// ---------------- counting-sort edges by src -------------------------------
__global__ void scatter_kernel(const int* __restrict__ ei, const float* __restrict__ ea,
                               const int* __restrict__ off, int* __restrict__ cur,
                               int* __restrict__ src_s, int* __restrict__ dst_s,
                               float* __restrict__ ea_s) {
  int e = blockIdx.x * 256 + threadIdx.x;
  if (e >= E_TOT) return;
  int s = ei[e];
  int pos = off[s] + atomicAdd(&cur[s], 1);
  src_s[pos] = s;
  dst_s[pos] = ei[E_TOT + e];
#pragma unroll
  for (int j = 0; j < 8; ++j) ea_s[(size_t)pos * 8 + j] = ea[(size_t)e * 8 + j];
}

// ---------------- permute ew2 -> Wp[(kb*2+oh)*128 + c][i] bf16 -------------
// c = kc*32 + o' with k = kb*4+kc, o = oh*32+o'
__global__ void cvt_wp(const float* __restrict__ ew2, u16* __restrict__ wp,
                       int K, int DINp) {
  int idx = blockIdx.x * 256 + threadIdx.x;  // (kbh, c)
  int c = idx & 127, kbh = idx >> 7;
  int kb = kbh >> 1, oh = kbh & 1;
  int k = kb * 4 + (c >> 5), o = oh * 32 + (c & 31);
  const float* src = ew2 + (size_t)k * (DINp * 64) + o;
  u16* dst = wp + (size_t)idx * DINp;
  for (int i = 0; i < DINp; ++i) dst[i] = f2bf(src[(size_t)i * 64]);
}

// ---------------- fused: M-build (MFMA) + per-edge fold + scatter ----------
// grid = 469 node-groups x 2 o-halves; block = 512 threads (8 waves).
// Double-buffered Wp staging; M chunk round-trips LDS as bf16 with
// full-(v&15) granule swizzle; H recomputed per step from reg-resident ea.
template <int DIN>
__global__ __launch_bounds__(512, 4) void fused_conv(
    const u16* __restrict__ Wp, const float* __restrict__ ew1,
    const float* __restrict__ eb1, const float* __restrict__ eb2,
    const float* __restrict__ xin, const float* __restrict__ eas,
    const int* __restrict__ src_s, const int* __restrict__ dst_s,
    const int* __restrict__ node_off, float* __restrict__ agg, int K) {
  constexpr int KF = DIN / 32;  // mfma k-fragments (i-dim)
  constexpr int NB = DIN / 8;   // 16B granules per Wp row
  constexpr int SLAB = 128 * DIN * 2;      // bytes per Wp slab
  constexpr int L_XB = 0;                  // [64][DIN] u16
  constexpr int L_W0 = 64 * DIN * 2;       // Wp buf 0
  constexpr int L_W1 = L_W0 + SLAB;        // Wp buf 1
  constexpr int L_MS = L_W1 + SLAB;        // [64][128] bf16 (granule-swizzled)
  constexpr int L_HS = L_MS + 16384;       // [512][4] bf16 (8B/slot)
  __shared__ __attribute__((aligned(16))) char smem[L_HS + 4096];

  const int t = threadIdx.x;
  const int lane = t & 63, wave = t >> 6;
  const int u = lane & 15, q = lane >> 4;
  const int grp = blockIdx.x >> 1, oh = blockIdx.x & 1;
  const int v0 = grp * 64;
  const int e0 = node_off[v0];
  const int v1 = (v0 + 64 < N_TOT) ? v0 + 64 : N_TOT;
  int Eblk = node_off[v1] - e0;
  if (Eblk > 512) Eblk = 512;
  const int nsteps = K >> 2;

  // prologue: stage Wp slab 0 into buf0 (swizzled granules)
  {
    const u16* gsl = Wp + (size_t)(0 * 2 + oh) * (128 * DIN);
#pragma unroll
    for (int j = 0; j < NB / 4; ++j) {
      int s = j * 512 + t;
      int c = s / NB, ib = s % NB;
      gload_lds16(gsl + (c * NB + (ib ^ (c & (NB - 1)))) * 8, smem + L_W0 + s * 16);
    }
  }

  // stage x group (bf16)
  {
    int row = t >> 3, i0 = (t & 7) * (DIN / 8);
    u16* xb = (u16*)(smem + L_XB) + row * DIN + i0;
    int vg = v0 + row;
#pragma unroll
    for (int j = 0; j < DIN / 8; ++j)
      xb[j] = (vg < N_TOT) ? f2bf(xin[(size_t)vg * DIN + i0 + j]) : (u16)0;
  }

  // own-slot edge attrs in registers (slot = t)
  f32x4 ea0 = (f32x4){0.f, 0.f, 0.f, 0.f}, ea1 = (f32x4){0.f, 0.f, 0.f, 0.f};
  if (t < Eblk) {
    const float* pe = eas + (size_t)(e0 + t) * 8;
    ea0 = *(const f32x4*)pe;
    ea1 = *(const f32x4*)(pe + 4);
  }

  // fold-task registers: task (slot = t>>1 + p*256, oq = t&1)
  const int oq = t & 1;
  int slotp[2], vofs[2], vsw[2], vls[2];
#pragma unroll
  for (int p = 0; p < 2; ++p) {
    int s = (t >> 1) + p * 256;
    slotp[p] = s;
    int vl = (s < Eblk) ? (src_s[e0 + s] - v0) : 0;
    vls[p] = vl;
    vofs[p] = L_MS + vl * 256;
    vsw[p] = vl & 15;
  }
  f32x4 msg[2][4];
#pragma unroll
  for (int p = 0; p < 2; ++p)
#pragma unroll
    for (int j = 0; j < 4; ++j) msg[p][j] = (f32x4){0.f, 0.f, 0.f, 0.f};

  __syncthreads();  // xb visible; prologue gload drained here too

  // cache x fragments (B-operand: B[k=i][n=v])
  short8 bfr[4][KF];
#pragma unroll
  for (int vt = 0; vt < 4; ++vt)
#pragma unroll
    for (int kf = 0; kf < KF; ++kf)
      bfr[vt][kf] =
          *(const short8*)(smem + L_XB + ((vt * 16 + u) * DIN + (kf * 4 + q) * 8) * 2);

  for (int kb = 0; kb < nsteps; ++kb) {
    __syncthreads();  // (a): staged slab for kb complete; prior fold done

    // H chunk for own slot (vectorized over 4 k; ew1 addrs uniform)
    {
      const int kk = kb * 4;
      f32x4 a = *(const f32x4*)(eb1 + kk);
      a += ea0.x * (*(const f32x4*)(ew1 + 0 * K + kk));
      a += ea0.y * (*(const f32x4*)(ew1 + 1 * K + kk));
      a += ea0.z * (*(const f32x4*)(ew1 + 2 * K + kk));
      a += ea0.w * (*(const f32x4*)(ew1 + 3 * K + kk));
      a += ea1.x * (*(const f32x4*)(ew1 + 4 * K + kk));
      a += ea1.y * (*(const f32x4*)(ew1 + 5 * K + kk));
      a += ea1.z * (*(const f32x4*)(ew1 + 6 * K + kk));
      a += ea1.w * (*(const f32x4*)(ew1 + 7 * K + kk));
      ushort4 hv;
      hv.x = f2bf(a.x > 0.f ? a.x : 0.f);
      hv.y = f2bf(a.y > 0.f ? a.y : 0.f);
      hv.z = f2bf(a.z > 0.f ? a.z : 0.f);
      hv.w = f2bf(a.w > 0.f ? a.w : 0.f);
      *(ushort4*)(smem + L_HS + t * 8) = hv;
    }

    // MFMA: M[c = wave*16 + q*4 + reg][v = vt*16 + u], then write bf16 to LDS
    {
      f32x4 acc[4];
#pragma unroll
      for (int vt = 0; vt < 4; ++vt) acc[vt] = (f32x4){0.f, 0.f, 0.f, 0.f};
      const int crow = wave * 16 + u;
      const char* wbase = smem + ((kb & 1) ? L_W1 : L_W0);
#pragma unroll
      for (int kf = 0; kf < KF; ++kf) {
        short8 afr = *(const short8*)(
            wbase + (crow * DIN + (((kf * 4 + q) ^ (crow & (NB - 1))) * 8)) * 2);
#pragma unroll
        for (int vt = 0; vt < 4; ++vt)
          acc[vt] = __builtin_amdgcn_mfma_f32_16x16x32_bf16(afr, bfr[vt][kf], acc[vt], 0, 0, 0);
      }
#pragma unroll
      for (int vt = 0; vt < 4; ++vt) {
        int v = vt * 16 + u;
        uint2 pk;
        pk.x = ((u32)f2bf(acc[vt].y) << 16) | f2bf(acc[vt].x);
        pk.y = ((u32)f2bf(acc[vt].w) << 16) | f2bf(acc[vt].z);
        int bbG = ((wave << 1) | (q >> 1)) ^ u;  // full-u swizzle: 2-way max
        *(uint2*)(smem + L_MS + v * 256 + bbG * 16 + (q & 1) * 8) = pk;
      }
    }
    __syncthreads();  // (b): M + HS visible

    // stage next Wp slab into the other buffer (in flight across the fold)
    if (kb + 1 < nsteps) {
      const u16* gsl = Wp + (size_t)((kb + 1) * 2 + oh) * (128 * DIN);
      char* dst = smem + (((kb + 1) & 1) ? L_W1 : L_W0);
#pragma unroll
      for (int j = 0; j < NB / 4; ++j) {
        int s = j * 512 + t;
        int c = s / NB, ib = s % NB;
        gload_lds16(gsl + (c * NB + (ib ^ (c & (NB - 1)))) * 8, dst + s * 16);
      }
    }

    // fold M-chunk into msg regs
#pragma unroll
    for (int p = 0; p < 2; ++p) {
      if (wave * 32 + p * 256 < Eblk) {
        ushort4 h4 = *(const ushort4*)(smem + L_HS + slotp[p] * 8);
        const u16* hp = (const u16*)&h4;
#pragma unroll
        for (int kc = 0; kc < 4; ++kc) {
          float h = bf2f(hp[kc]);
#pragma unroll
          for (int s = 0; s < 2; ++s) {
            int bb = (kc * 4 + oq * 2 + s) ^ vsw[p];
            uint4 m8 = *(const uint4*)(smem + vofs[p] + bb * 16);
            f32x4 lo, hi;
            lo.x = __uint_as_float(m8.x << 16);
            lo.y = __uint_as_float(m8.x & 0xffff0000u);
            lo.z = __uint_as_float(m8.y << 16);
            lo.w = __uint_as_float(m8.y & 0xffff0000u);
            hi.x = __uint_as_float(m8.z << 16);
            hi.y = __uint_as_float(m8.z & 0xffff0000u);
            hi.z = __uint_as_float(m8.w << 16);
            hi.w = __uint_as_float(m8.w & 0xffff0000u);
            msg[p][s * 2 + 0] += h * lo;
            msg[p][s * 2 + 1] += h * hi;
          }
        }
      }
    }
  }
  __syncthreads();

  // bias term bt[v][o'] = sum_i x[v,i]*eb2[i*64 + oh*32 + o']  (into Ms area)
  {
    int v = t >> 3, o4 = (t & 7) * 4;
    f32x4 acc = (f32x4){0.f, 0.f, 0.f, 0.f};
    const u16* xb = (const u16*)(smem + L_XB) + v * DIN;
    const float* ep = eb2 + oh * 32 + o4;
    for (int i = 0; i < DIN; ++i) {
      float xv = bf2f(xb[i]);
      f32x4 w4 = *(const f32x4*)(ep + (size_t)i * 64);
      acc += xv * w4;
    }
    *(f32x4*)(smem + L_MS + (v * 32 + o4) * 4) = acc;
  }
  __syncthreads();

  // scatter: agg[dst, oh*32 + oq*16 + 0..15] += msg + bt
#pragma unroll
  for (int p = 0; p < 2; ++p) {
    int slot = slotp[p];
    if (slot < Eblk) {
      int d = dst_s[e0 + slot];
      float* ap = agg + (size_t)d * 64 + oh * 32 + oq * 16;
      const float* bt = (const float*)(smem + L_MS) + vls[p] * 32 + oq * 16;
#pragma unroll
      for (int j = 0; j < 4; ++j) {
        f32x4 m = msg[p][j];
        atomicAdd(ap + j * 4 + 0, m.x + bt[j * 4 + 0]);
        atomicAdd(ap + j * 4 + 1, m.y + bt[j * 4 + 1]);
        atomicAdd(ap + j * 4 + 2, m.z + bt[j * 4 + 2]);
        atomicAdd(ap + j * 4 + 3, m.w + bt[j * 4 + 3]);
      }
    }
  }
}

// ---------------- out = relu(agg/deg + x@root + cb) ----------------
__global__ void node_update(const float* __restrict__ agg, const float* __restrict__ deg,
                            const float* __restrict__ xin, const float* __restrict__ root,
                            const float* __restrict__ cbv, float* __restrict__ xout,
                            int din) {
  __shared__ float rl[4096];
  const int t = threadIdx.x;
  for (int i = t; i < din * 64; i += 256) rl[i] = root[i];
  __syncthreads();
  const int o = t & 63;
  const int n = blockIdx.x * 4 + (t >> 6);
  if (n >= N_TOT) return;
  float acc = cbv[o];
  for (int i = 0; i < din; ++i) acc += xin[(size_t)n * din + i] * rl[i * 64 + o];
  float d = deg[n];
  d = d > 1.f ? d : 1.f;
  acc += agg[(size_t)n * 64 + o] / d;
  xout[(size_t)n * 64 + o] = acc > 0.f ? acc : 0.f;
}

// ---------------- graph sum pool ----------------
__global__ void pool_kernel(const float* __restrict__ x3, const int* __restrict__ batch,
                            float* __restrict__ gsum) {
  int t = blockIdx.x * 256 + threadIdx.x;
  if (t >= N_TOT * 64) return;
  int n = t >> 6, o = t & 63;
  atomicAdd(&gsum[(size_t)batch[n] * 64 + o], x3[t]);
}

// ---------------- readout MLP ----------------
__global__ void readout_kernel(const float* __restrict__ gsum, const float* __restrict__ gcnt,
                               const float* __restrict__ mw1, const float* __restrict__ mb1,
                               const float* __restrict__ mw2, const float* __restrict__ mb2,
                               float* __restrict__ out) {
  __shared__ float gv[4][64];
  const int t = threadIdx.x;
  const int o = t & 63, loc = t >> 6;
  const int g = blockIdx.x * 4 + loc;
  float v = 0.f;
  if (g < G_TOT) {
    float c = gcnt[g];
    c = c > 1.f ? c : 1.f;
    v = gsum[(size_t)g * 64 + o] / c;
  }
  gv[loc][o] = v;
  __syncthreads();
  float acc = mb1[o];
  for (int i = 0; i < 64; ++i) acc += gv[loc][i] * mw1[i * 64 + o];
  acc = acc > 0.f ? acc : 0.f;
  float p = acc * mw2[o];
#pragma unroll
  for (int off = 32; off > 0; off >>= 1) p += __shfl_down(p, off, 64);
  if (o == 0 && g < G_TOT) out[g] = p + mb2[0];
}

extern "C" void kernel_launch(void* const* d_in, const int* in_sizes, int n_in,
                              void* d_out, int out_size, void* d_ws, size_t ws_size,
                              hipStream_t stream) {
  const float* x     = (const float*)d_in[0];
  const int*   ei    = (const int*)d_in[1];
  const float* ea    = (const float*)d_in[2];
  const int*   batch = (const int*)d_in[3];
  const float* ew1[3] = {(const float*)d_in[4],  (const float*)d_in[10], (const float*)d_in[16]};
  const float* eb1[3] = {(const float*)d_in[5],  (const float*)d_in[11], (const float*)d_in[17]};
  const float* ew2[3] = {(const float*)d_in[6],  (const float*)d_in[12], (const float*)d_in[18]};
  const float* eb2[3] = {(const float*)d_in[7],  (const float*)d_in[13], (const float*)d_in[19]};
  const float* root[3] = {(const float*)d_in[8],  (const float*)d_in[14], (const float*)d_in[20]};
  const float* cbv[3]  = {(const float*)d_in[9],  (const float*)d_in[15], (const float*)d_in[21]};
  const float* mw1 = (const float*)d_in[22];
  const float* mb1 = (const float*)d_in[23];
  const float* mw2 = (const float*)d_in[24];
  const float* mb2 = (const float*)d_in[25];
  float* out = (float*)d_out;

  char* p = (char*)d_ws;
  auto carve = [&p](size_t bytes) {
    char* r = p;
    p += (bytes + 255) & ~(size_t)255;
    return r;
  };
  u16*   wp   = (u16*)carve((size_t)4096 * 64 * 64 * 2);  // permuted ew2, per-layer
  float* x1   = (float*)carve((size_t)N_TOT * 64 * 4);
  float* x2   = (float*)carve((size_t)N_TOT * 64 * 4);
  float* x3   = (float*)carve((size_t)N_TOT * 64 * 4);
  float* agg  = (float*)carve((size_t)N_TOT * 64 * 4);
  float* deg  = (float*)carve((size_t)N_TOT * 4);
  float* gsum = (float*)carve((size_t)G_TOT * 64 * 4);
  float* gcnt = (float*)carve((size_t)G_TOT * 4);
  int*   sd   = (int*)carve((size_t)N_TOT * 4);
  int*   noff = (int*)carve((size_t)(N_TOT + 1) * 4);
  int*   cur  = (int*)carve((size_t)N_TOT * 4);
  int*   srcs = (int*)carve((size_t)E_TOT * 4);
  int*   dsts = (int*)carve((size_t)E_TOT * 4);
  float* eass = (float*)carve((size_t)E_TOT * 8 * 4);

  hipMemsetAsync(deg, 0, (size_t)N_TOT * 4, stream);
  hipMemsetAsync(gsum, 0, (size_t)G_TOT * 64 * 4, stream);
  hipMemsetAsync(gcnt, 0, (size_t)G_TOT * 4, stream);
  hipMemsetAsync(sd, 0, (size_t)N_TOT * 4, stream);
  hipMemsetAsync(cur, 0, (size_t)N_TOT * 4, stream);

  prep_kernel<<<(E_TOT + 255) / 256, 256, 0, stream>>>(ei, batch, deg, gcnt, sd);
  scan_kernel<<<1, 1024, 0, stream>>>(sd, noff);
  scatter_kernel<<<(E_TOT + 255) / 256, 256, 0, stream>>>(ei, ea, noff, cur, srcs, dsts, eass);

  const float* xin_l[3]  = {x, x1, x2};
  float*       xout_l[3] = {x1, x2, x3};
  const int Ks[3]   = {2048, 4096, 4096};
  const int dins[3] = {32, 64, 64};
  const int grid_fused = ((N_TOT + 63) / 64) * 2;  // 938

  for (int L = 0; L < 3; ++L) {
    const int K = Ks[L], din = dins[L];
    cvt_wp<<<(K * 64) / 256, 256, 0, stream>>>(ew2[L], wp, K, din);
    hipMemsetAsync(agg, 0, (size_t)N_TOT * 64 * 4, stream);
    if (din == 32)
      fused_conv<32><<<grid_fused, 512, 0, stream>>>(wp, ew1[L], eb1[L], eb2[L], xin_l[L],
                                                     eass, srcs, dsts, noff, agg, K);
    else
      fused_conv<64><<<grid_fused, 512, 0, stream>>>(wp, ew1[L], eb1[L], eb2[L], xin_l[L],
                                                     eass, srcs, dsts, noff, agg, K);
    node_update<<<(N_TOT + 3) / 4, 256, 0, stream>>>(agg, deg, xin_l[L], root[L], cbv[L],
                                                     xout_l[L], din);
  }
  pool_kernel<<<(N_TOT * 64 + 255) / 256, 256, 0, stream>>>(x3, batch, gsum);
  readout_kernel<<<(G_TOT + 3) / 4, 256, 0, stream>>>(gsum, gcnt, mw1, mb1, mw2, mb2, out);
}